// Round 18
// baseline (1571.555 us; speedup 1.0000x reference)
//
#include <hip/hip_runtime.h>

// 2-layer LSTM (B=256, T=512, D=64, H=256) + FC(256->4).
// Round-18: u-DECOUPLED, HALF-SPLIT RECURRENCES. 32 groups x 7 blocks:
//   role 0,1 = alpha/beta: h0 recurrence, Whh0 half (units 128*hf..+128)
//   role 2,3 = gamma/delta: h1 recurrence, Whh1 half
//   role 4,5 = L1u-a/b: u1(s) = Wih1*h0(s) + bias1 (row halves)
//   role 6   = L0u: u0(s) = Wih0*x(s) + bias0 (all rows)
// Recurrence blocks wait on exactly ONE peer packet set per step; all u-waits
// are on data produced >=1 period earlier (pipeline-filled, first-try hit).
// Protocol = r8/r17 primitives: u64 {epoch32|2xf16} packets, relaxed
// agent-scope atomics, ring-4 slots, uniform guard tgt=s-2 (publish cflag=s+1
// at iter top), memset epoch-0 == data(-1)=0.
// ws: h0 1MB | h1 1MB | u0 4MB | u1 4MB | cflags 2KB (10.3MB total).

#define TT 512
#define HH 256
#define DD 64

typedef __attribute__((ext_vector_type(2))) _Float16 h2t;
typedef __attribute__((ext_vector_type(8))) _Float16 f16x8;
typedef __attribute__((ext_vector_type(4))) float f32x4;
typedef unsigned long long u64;
typedef unsigned u32;

__device__ __forceinline__ u32 pkh(float x, float y) {
    h2t h; h.x = (_Float16)x; h.y = (_Float16)y;
    return __builtin_bit_cast(u32, h);
}
__device__ __forceinline__ float sigf(float x) { return 1.f / (1.f + __expf(-x)); }
__device__ __forceinline__ float tanhf_(float x) {
    float e = __expf(2.f * x);
    return 1.f - 2.f / (e + 1.f);   // safe at +/-inf
}
__device__ __forceinline__ f16x8 ld8(const float* p) {
    float4 u = ((const float4*)p)[0];
    float4 v = ((const float4*)p)[1];
    f16x8 r = {(_Float16)u.x, (_Float16)u.y, (_Float16)u.z, (_Float16)u.w,
               (_Float16)v.x, (_Float16)v.y, (_Float16)v.z, (_Float16)v.w};
    return r;
}
__device__ __forceinline__ u32 ld32(const u32* p) {
    return __hip_atomic_load(p, __ATOMIC_RELAXED, __HIP_MEMORY_SCOPE_AGENT);
}
__device__ __forceinline__ void st32(u32* p, u32 v) {
    __hip_atomic_store(p, v, __ATOMIC_RELAXED, __HIP_MEMORY_SCOPE_AGENT);
}
__device__ __forceinline__ u64 ld64(const u64* p) {
    return __hip_atomic_load(p, __ATOMIC_RELAXED, __HIP_MEMORY_SCOPE_AGENT);
}
__device__ __forceinline__ void st64(u64* p, u64 v) {
    __hip_atomic_store(p, v, __ATOMIC_RELAXED, __HIP_MEMORY_SCOPE_AGENT);
}

#define MFMA16(A, B, C) __builtin_amdgcn_mfma_f32_16x16x32_f16((A), (B), (C), 0, 0, 0)

#define DECLF(ti) f16x8 A##ti##_0 = {}, A##ti##_1 = {}, A##ti##_2 = {}, A##ti##_3 = {};

__global__ __launch_bounds__(512, 2) void lstm_persist(
    const float* __restrict__ x,
    const float* __restrict__ Wih0, const float* __restrict__ Whh0,
    const float* __restrict__ bih0, const float* __restrict__ bhh0,
    const float* __restrict__ Wih1, const float* __restrict__ Whh1,
    const float* __restrict__ bih1, const float* __restrict__ bhh1,
    const float* __restrict__ fcW, const float* __restrict__ fcb,
    float* __restrict__ out,
    u64* wsu, u32* cflagsA)
{
    // LDS: sB 32 chunks x 144 halves (9216 B) | part2 [2][8][520] f32 (33280 B)
    __shared__ __align__(16) char ldsraw[9216 + 33280];
    _Float16* const sB16 = (_Float16*)ldsraw;
    u32* const sBu = (u32*)ldsraw;
    float (*const part2)[8][520] = (float(*)[8][520])(ldsraw + 9216);
    float (*const p1)[1032] = (float(*)[1032])(ldsraw + 9216);   // L0u view

    const int tid  = threadIdx.x;
    const int g    = blockIdx.x & 31;
    const int role = blockIdx.x >> 5;    // 0..6
    const int batch0 = g * 8;
    u64* const h0ring = wsu + (size_t)g * 4096;
    u64* const h1ring = wsu + 131072 + (size_t)g * 4096;
    u64* const u0ring = wsu + 262144 + (size_t)g * 16384;
    u64* const u1ring = wsu + 786432 + (size_t)g * 16384;
    u32* const cflag  = cflagsA + (size_t)g * 16;

    const int lane = tid & 63, w = tid >> 6;
    const int mw = w & 3, kh = w >> 2;
    const int bcol = lane & 15, kc = lane >> 4;

    for (int i = tid; i < 2304; i += 512) sBu[i] = 0;   // zero sB (pads + h(-1)=0)
    __syncthreads();

    if (role < 4) {
        // ===================== RECURRENCE BLOCKS =====================
        const int hf = role & 1;
        const bool L1 = role >= 2;
        const float* const W = L1 ? Whh1 : Whh0;
        u64* const hring = L1 ? h1ring : h0ring;
        const u64* const uring = L1 ? u1ring : u0ring;
        const int ng = L1 ? 1 : 3;                  // guard flag count
        const int gfi = (lane == 0) ? (role ^ 1) : (3 + lane);   // peer / roles 4,5

        DECLF(0) DECLF(1) DECLF(2) DECLF(3) DECLF(4) DECLF(5) DECLF(6) DECLF(7)
#define LREC(ti) { const int R_ = mw * 256 + hf * 128 + (ti) * 16 + (lane & 15);  \
        const float* rw_ = W + (size_t)R_ * 256 + kh * 128 + kc * 8;              \
        A##ti##_0 = ld8(rw_);      A##ti##_1 = ld8(rw_ + 32);                     \
        A##ti##_2 = ld8(rw_ + 64); A##ti##_3 = ld8(rw_ + 96); }
        LREC(0) LREC(1) LREC(2) LREC(3) LREC(4) LREC(5) LREC(6) LREC(7)
#undef LREC

        const int j2 = w;           // act duty: batch
        const int up = lane;        // act duty: local unit-pair 0..63
        float c0_ = 0.f, c1_ = 0.f;

        for (int s = 0; s < TT; ++s) {
            if (tid == 0) st32(&cflag[role], (u32)(s + 1));
            u32 cp = 0;
            if (lane < ng) cp = ld32(&cflag[gfi]);

            // ---- MFMA: gates partials from sB (h(s-1) full) ----
            {
                const f16x8 B0_ = *(const f16x8*)(sB16 + (kh*16 + 0*4 + kc)*144 + bcol*8);
                const f16x8 B1_ = *(const f16x8*)(sB16 + (kh*16 + 1*4 + kc)*144 + bcol*8);
                const f16x8 B2_ = *(const f16x8*)(sB16 + (kh*16 + 2*4 + kc)*144 + bcol*8);
                const f16x8 B3_ = *(const f16x8*)(sB16 + (kh*16 + 3*4 + kc)*144 + bcol*8);
#define MTR(ti) { f32x4 C_ = {0,0,0,0};                                           \
                C_ = MFMA16(A##ti##_0, B0_, C_); C_ = MFMA16(A##ti##_1, B1_, C_); \
                C_ = MFMA16(A##ti##_2, B2_, C_); C_ = MFMA16(A##ti##_3, B3_, C_); \
                if (bcol < 8)                                                     \
                    *(f32x4*)&part2[kh][bcol][mw*128 + (ti)*16 + kc*4] = C_; }
                MTR(0) MTR(1) MTR(2) MTR(3) MTR(4) MTR(5) MTR(6) MTR(7)
#undef MTR
            }
            __syncthreads();   // part2 ready; sB(s) reads done

            // ---- u packets (aged -> usually first-try) ----
            const u32 eu = (u32)(s + 1);
            const u64* ub_ = uring + (size_t)(s & 3) * 4096 + (size_t)j2 * 512
                             + hf * 64 + up;
            const u64 *ua0 = ub_, *ua1 = ub_ + 128, *ua2 = ub_ + 256, *ua3 = ub_ + 384;
            u64 v0 = ld64(ua0), v1 = ld64(ua1), v2 = ld64(ua2), v3 = ld64(ua3);
            for (;;) {
                bool k0 = ((u32)(v0 >> 32) == eu), k1 = ((u32)(v1 >> 32) == eu);
                bool k2 = ((u32)(v2 >> 32) == eu), k3 = ((u32)(v3 >> 32) == eu);
                if (k0 & k1 & k2 & k3) break;
                if (!k0) v0 = ld64(ua0);
                if (!k1) v1 = ld64(ua1);
                if (!k2) v2 = ld64(ua2);
                if (!k3) v3 = ld64(ua3);
            }
            float e0, o0, e1, o1, e2, o2, e3, o3;
#define GG(gi, vv) { const float2 xa = *(const float2*)&part2[0][j2][(gi)*128 + 2*up]; \
            const float2 xb = *(const float2*)&part2[1][j2][(gi)*128 + 2*up];          \
            const h2t uh = __builtin_bit_cast(h2t, (u32)(vv));                         \
            e##gi = xa.x + xb.x + (float)uh.x; o##gi = xa.y + xb.y + (float)uh.y; }
            GG(0, v0) GG(1, v1) GG(2, v2) GG(3, v3)
#undef GG
            {   // even unit
                float ie = sigf(e0), fe = sigf(e1), ge = tanhf_(e2), oe = sigf(e3);
                c0_ = fe * c0_ + ie * ge;
                e0 = oe * tanhf_(c0_);            // reuse e0 = h_even
            }
            {   // odd unit
                float io = sigf(o0), fo = sigf(o1), go = tanhf_(o2), oo = sigf(o3);
                c1_ = fo * c1_ + io * go;
                o0 = oo * tanhf_(c1_);            // o0 = h_odd
            }
            const u32 hw = pkh(e0, o0);

            // own half straight into sB (for step s+1)
            sBu[(hf*16 + (up >> 2)) * 72 + j2 * 4 + (up & 3)] = hw;

            // ring-overwrite guard (slot s&3 held h(s-4)); tgt = s-2
            {
                const int tgt = s - 2;
                while (!__all(lane >= ng || (int)cp >= tgt)) {
                    __builtin_amdgcn_s_sleep(1);
                    if (lane < ng) cp = ld32(&cflag[gfi]);
                }
            }
            // publish h(s)
            st64(hring + (size_t)(s & 3) * 1024 + (size_t)hf * 512 + j2 * 64 + up,
                 ((u64)eu << 32) | (u64)hw);

            // stage peer half of h(s) -- THE single-peer wait
            {
                const u64* pa_ = hring + (size_t)(s & 3) * 1024
                                 + (size_t)(1 - hf) * 512 + j2 * 64 + up;
                u64 pv = ld64(pa_);
                while ((u32)(pv >> 32) != eu) pv = ld64(pa_);
                sBu[((1 - hf)*16 + (up >> 2)) * 72 + j2 * 4 + (up & 3)] = (u32)pv;
            }
            __syncthreads();   // sB(s+1) complete; part2 free
        }

        // ---- final FC on h1(511), by gamma (role 2): sB holds full h1(511) ----
        if (role == 2) {
            const int j = tid >> 6, l2 = tid & 63;
            const int o = l2 >> 4, kk = l2 & 15;
            float ssum = 0.f;
#pragma unroll
            for (int m = 0; m < 16; ++m) {
                int k = kk * 16 + m;
                ssum += (float)sB16[(k >> 3) * 144 + j * 8 + (k & 7)] * fcW[o * HH + k];
            }
#pragma unroll
            for (int off = 8; off; off >>= 1) ssum += __shfl_down(ssum, off);
            if (kk == 0) out[(batch0 + j) * 4 + o] = ssum + fcb[o];
        }
    } else if (role < 6) {
        // ===================== L1u: u1(s) = Wih1 . h0(s) + bias1 =====================
        const int rh = role - 4;
        DECLF(0) DECLF(1) DECLF(2) DECLF(3) DECLF(4) DECLF(5) DECLF(6) DECLF(7)
#define LU1(ti) { const int R_ = rh * 512 + mw * 128 + (ti) * 16 + (lane & 15);   \
        const float* rw_ = Wih1 + (size_t)R_ * 256 + kh * 128 + kc * 8;           \
        A##ti##_0 = ld8(rw_);      A##ti##_1 = ld8(rw_ + 32);                     \
        A##ti##_2 = ld8(rw_ + 64); A##ti##_3 = ld8(rw_ + 96); }
        LU1(0) LU1(1) LU1(2) LU1(3) LU1(4) LU1(5) LU1(6) LU1(7)
#undef LU1
        // biases for my 4 row-pairs (k = 0..3)
        float bA0, bA1, bB0, bB1, bC0, bC1, bD0, bD1;
        {
            int r;
            r = rh*512 + 2*(lane +   0); bA0 = bih1[r] + bhh1[r]; bA1 = bih1[r+1] + bhh1[r+1];
            r = rh*512 + 2*(lane +  64); bB0 = bih1[r] + bhh1[r]; bB1 = bih1[r+1] + bhh1[r+1];
            r = rh*512 + 2*(lane + 128); bC0 = bih1[r] + bhh1[r]; bC1 = bih1[r+1] + bhh1[r+1];
            r = rh*512 + 2*(lane + 192); bD0 = bih1[r] + bhh1[r]; bD1 = bih1[r+1] + bhh1[r+1];
        }

        for (int s = 0; s < TT; ++s) {
            if (tid == 0) st32(&cflag[role], (u32)(s + 1));
            u32 cp = 0;
            if (lane < 2) cp = ld32(&cflag[2 + lane]);   // gamma, delta

            // stage h0(s): 2 packets/thread (paces to the h0 chain)
            const u32 eu = (u32)(s + 1);
            {
                const u64* hb = h0ring + (size_t)(s & 3) * 1024;
                const u64 *a0 = hb + tid, *a1 = hb + 512 + tid;
                u64 v0 = ld64(a0), v1 = ld64(a1);
                for (;;) {
                    bool k0 = ((u32)(v0 >> 32) == eu), k1 = ((u32)(v1 >> 32) == eu);
                    if (k0 & k1) break;
                    if (!k0) v0 = ld64(a0);
                    if (!k1) v1 = ld64(a1);
                }
                const int jj = (tid >> 6) & 7, uu = tid & 63;
                sBu[(     (uu >> 2)) * 72 + jj * 4 + (uu & 3)] = (u32)v0;   // half 0
                sBu[(16 + (uu >> 2)) * 72 + jj * 4 + (uu & 3)] = (u32)v1;   // half 1
            }
            __syncthreads();

            {
                const f16x8 B0_ = *(const f16x8*)(sB16 + (kh*16 + 0*4 + kc)*144 + bcol*8);
                const f16x8 B1_ = *(const f16x8*)(sB16 + (kh*16 + 1*4 + kc)*144 + bcol*8);
                const f16x8 B2_ = *(const f16x8*)(sB16 + (kh*16 + 2*4 + kc)*144 + bcol*8);
                const f16x8 B3_ = *(const f16x8*)(sB16 + (kh*16 + 3*4 + kc)*144 + bcol*8);
#define MTR(ti) { f32x4 C_ = {0,0,0,0};                                           \
                C_ = MFMA16(A##ti##_0, B0_, C_); C_ = MFMA16(A##ti##_1, B1_, C_); \
                C_ = MFMA16(A##ti##_2, B2_, C_); C_ = MFMA16(A##ti##_3, B3_, C_); \
                if (bcol < 8)                                                     \
                    *(f32x4*)&part2[kh][bcol][mw*128 + (ti)*16 + kc*4] = C_; }
                MTR(0) MTR(1) MTR(2) MTR(3) MTR(4) MTR(5) MTR(6) MTR(7)
#undef MTR
            }
            __syncthreads();

            // guard u1 slot overwrite (tgt = s-2), then store u1(s)
            {
                const int tgt = s - 2;
                while (!__all(lane >= 2 || (int)cp >= tgt)) {
                    __builtin_amdgcn_s_sleep(1);
                    if (lane < 2) cp = ld32(&cflag[2 + lane]);
                }
            }
            {
                const u64 ep = (u64)eu << 32;
                u64* ubst = u1ring + (size_t)(s & 3) * 4096 + (size_t)w * 512 + rh * 256;
#define STU(kk_, bz0n, bz1n) { const int rp_ = lane + 64*(kk_); const int r0_ = 2*rp_; \
                float lo_ = part2[0][w][r0_] + part2[1][w][r0_] + bz0n;                \
                float hi_ = part2[0][w][r0_ + 1] + part2[1][w][r0_ + 1] + bz1n;        \
                st64(ubst + rp_, ep | (u64)pkh(lo_, hi_)); }
                STU(0, bA0, bA1) STU(1, bB0, bB1) STU(2, bC0, bC1) STU(3, bD0, bD1)
#undef STU
            }
        }
    } else {
        // ===================== L0u: u0(s) = Wih0 . x(s) + bias0 =====================
        DECLF(0) DECLF(1) DECLF(2) DECLF(3) DECLF(4) DECLF(5) DECLF(6) DECLF(7)
#define LU0(ti) { const int R_ = w * 128 + (ti) * 16 + (lane & 15);               \
        const float* rw_ = Wih0 + (size_t)R_ * 64 + kc * 8;                       \
        A##ti##_0 = ld8(rw_); A##ti##_1 = ld8(rw_ + 32); }
        LU0(0) LU0(1) LU0(2) LU0(3) LU0(4) LU0(5) LU0(6) LU0(7)
#undef LU0

        for (int s = 0; s < TT; ++s) {
            if (tid == 0) st32(&cflag[role], (u32)(s + 1));
            u32 cp = 0;
            if (lane < 2) cp = ld32(&cflag[lane]);   // alpha, beta

            if (tid < 128) {   // stage x(s) -> chunks 0..7
                const int j = tid >> 4, c = tid & 15;
                const float4 v = *(const float4*)(
                    x + ((size_t)(batch0 + j) * TT + s) * DD + c * 4);
                const int bi = (c >> 1) * 72 + j * 4 + (c & 1) * 2;
                sBu[bi]     = pkh(v.x, v.y);
                sBu[bi + 1] = pkh(v.z, v.w);
            }
            __syncthreads();

            {
                const f16x8 B0_ = *(const f16x8*)(sB16 + kc * 144 + bcol * 8);
                const f16x8 B1_ = *(const f16x8*)(sB16 + (4 + kc) * 144 + bcol * 8);
#define MT0(ti) { f32x4 C_ = {0,0,0,0};                                           \
                C_ = MFMA16(A##ti##_0, B0_, C_); C_ = MFMA16(A##ti##_1, B1_, C_); \
                if (bcol < 8)                                                     \
                    *(f32x4*)&p1[bcol][w*128 + (ti)*16 + kc*4] = C_; }
                MT0(0) MT0(1) MT0(2) MT0(3) MT0(4) MT0(5) MT0(6) MT0(7)
#undef MT0
            }
            __syncthreads();

            {
                const int tgt = s - 2;
                while (!__all(lane >= 2 || (int)cp >= tgt)) {
                    __builtin_amdgcn_s_sleep(1);
                    if (lane < 2) cp = ld32(&cflag[lane]);
                }
            }
            {
                const u64 ep = (u64)(u32)(s + 1) << 32;
                u64* ubst = u0ring + (size_t)(s & 3) * 4096 + (size_t)w * 512;
#pragma unroll
                for (int k = 0; k < 8; ++k) {
                    const int rp = lane + 64 * k, r0 = 2 * rp;
                    const float lo = p1[w][r0] + bih0[r0] + bhh0[r0];
                    const float hi = p1[w][r0 + 1] + bih0[r0 + 1] + bhh0[r0 + 1];
                    st64(ubst + rp, ep | (u64)pkh(lo, hi));
                }
            }
        }
    }
}

extern "C" void kernel_launch(void* const* d_in, const int* in_sizes, int n_in,
                              void* d_out, int out_size, void* d_ws, size_t ws_size,
                              hipStream_t stream)
{
    (void)in_sizes; (void)n_in; (void)out_size; (void)ws_size;
    const float* x    = (const float*)d_in[0];
    const float* Wih0 = (const float*)d_in[1];
    const float* Whh0 = (const float*)d_in[2];
    const float* bih0 = (const float*)d_in[3];
    const float* bhh0 = (const float*)d_in[4];
    const float* Wih1 = (const float*)d_in[5];
    const float* Whh1 = (const float*)d_in[6];
    const float* bih1 = (const float*)d_in[7];
    const float* bhh1 = (const float*)d_in[8];
    const float* fcW  = (const float*)d_in[9];
    const float* fcb  = (const float*)d_in[10];
    float* out = (float*)d_out;

    // ws (u64 units): h0 [32g][4][1024] | h1 +131072 | u0 +262144 [32g][4][4096]
    //                 | u1 +786432 | cflags @ byte 10485760
    u64* wsu    = (u64*)d_ws;
    u32* cflags = (u32*)((char*)d_ws + 10485760);

    hipMemsetAsync(d_ws, 0, 10485760 + 2048, stream);   // epoch 0 == data(-1)=0

    lstm_persist<<<dim3(224), dim3(512), 0, stream>>>(
        x, Wih0, Whh0, bih0, bhh0, Wih1, Whh1, bih1, bhh1, fcW, fcb, out,
        wsu, cflags);
}

// Round 19
// 1243.683 us; speedup vs baseline: 1.2636x; 1.2636x over previous
//
#include <hip/hip_runtime.h>

// 2-layer LSTM (B=256, T=512, D=64, H=256) + FC(256->4).
// FINAL (round-8/17 best: 1246us verified). 32 groups x 8 blocks; blocks
// 0-3: layer 0 quadrant q, 4-7: layer 1 quadrant q. Systolic skew: iter s
// computes h0(s) on L0 and h1(s-1) on L1.
// Exchange: u64 packets {epoch32|2xf16} via relaxed agent-scope atomics
// (the only verified-correct cross-block path; per-XCD L2s non-coherent),
// ring-4 slots, slack-2 cflag guard, 2 barriers/step. MFMA 16x16x32 f16 with
// weights register-resident as named A-fragment SSA values (4Mx2K waves,
// ~104 VGPR). Own-quadrant h written straight into own sB (no ring RTT).
//
// Plateau evidence (10 structural variants, all regressed or null):
//   decoupled flags / parallel staging issue / sc0-L2 fast path (hang) /
//   early pre-issue / two-stream x2 / skew-2 fresh-last / comm-wave
//   specialization / all-K-per-wave (spill) / u-term decoupling (8x traffic).
// Period = compute (~0.75us) + L3 visibility (~1.7us); the latter is
// structural: serial recurrence, state split across 8 CUs (register
// capacity forces the split), no independent work to hide it under.

#define TT 512
#define HH 256
#define DD 64

typedef __attribute__((ext_vector_type(2))) _Float16 h2t;
typedef __attribute__((ext_vector_type(8))) _Float16 f16x8;
typedef __attribute__((ext_vector_type(4))) float f32x4;
typedef unsigned long long u64;
typedef unsigned u32;

__device__ __forceinline__ u32 pkh(float x, float y) {
    h2t h; h.x = (_Float16)x; h.y = (_Float16)y;
    return __builtin_bit_cast(u32, h);
}
__device__ __forceinline__ float sigf(float x) { return 1.f / (1.f + __expf(-x)); }
__device__ __forceinline__ float tanhf_(float x) {
    float e = __expf(2.f * x);
    return 1.f - 2.f / (e + 1.f);   // safe at +/-inf
}
__device__ __forceinline__ f16x8 ld8(const float* p) {
    float4 u = ((const float4*)p)[0];
    float4 v = ((const float4*)p)[1];
    f16x8 r = {(_Float16)u.x, (_Float16)u.y, (_Float16)u.z, (_Float16)u.w,
               (_Float16)v.x, (_Float16)v.y, (_Float16)v.z, (_Float16)v.w};
    return r;
}
__device__ __forceinline__ u32 ld32(const u32* p) {
    return __hip_atomic_load(p, __ATOMIC_RELAXED, __HIP_MEMORY_SCOPE_AGENT);
}
__device__ __forceinline__ void st32(u32* p, u32 v) {
    __hip_atomic_store(p, v, __ATOMIC_RELAXED, __HIP_MEMORY_SCOPE_AGENT);
}
__device__ __forceinline__ u64 ld64(const u64* p) {
    return __hip_atomic_load(p, __ATOMIC_RELAXED, __HIP_MEMORY_SCOPE_AGENT);
}
__device__ __forceinline__ void st64(u64* p, u64 v) {
    __hip_atomic_store(p, v, __ATOMIC_RELAXED, __HIP_MEMORY_SCOPE_AGENT);
}

__global__ __launch_bounds__(512, 2) void lstm_persist(
    const float* __restrict__ x,
    const float* __restrict__ Wih0, const float* __restrict__ Whh0,
    const float* __restrict__ bih0, const float* __restrict__ bhh0,
    const float* __restrict__ Wih1, const float* __restrict__ Whh1,
    const float* __restrict__ bih1, const float* __restrict__ bhh1,
    const float* __restrict__ fcW, const float* __restrict__ fcb,
    float* __restrict__ out,
    u64* h0ring, u64* h1ring, u32* cflagsA)
{
    __shared__ __align__(16) _Float16 sB[9216];        // 64 chunks x 144 halves
    __shared__ __align__(16) float part2[2][8][276];   // k-split partials

    const int tid  = threadIdx.x;
    const int g    = blockIdx.x & 31;
    const int role = blockIdx.x >> 5;
    const bool isL1 = role >= 4;
    const int q = role & 3;
    const int batch0 = g * 8;
    u64* ring0 = h0ring + (size_t)g * 4096;   // [slot4][q4][j8][hp32]
    u64* ring1 = h1ring + (size_t)g * 4096;
    u32* cflag = cflagsA + (size_t)g * 16;

    const int lane = tid & 63, w = tid >> 6;
    const int mw = w & 3, kh = w >> 2;
    const int bcol = lane & 15, kc = lane >> 4;

    // packet geometry (fixed per thread): p = tid + pp*512; n = p&127 same both
    const int n_ = tid & 127;
    const int jA = tid >> 7;          // batch for pp=0
    const int jB = 4 + (tid >> 7);    // batch for pp=1
    const int nq = n_ >> 5;           // quadrant of my packets

    // ---- A-fragment rows: wave mw owns gate mw; tiles ti=0..3 ----
    const int R0 = mw * 256 + 64 * q + (lane & 15);
    const int R1 = R0 + 16, R2 = R0 + 32, R3 = R0 + 48;

#define DECL_TI(ti) f16x8 A##ti##_0={},A##ti##_1={},A##ti##_2={},A##ti##_3={}, \
                          A##ti##_4={},A##ti##_5={},A##ti##_6={},A##ti##_7={};
    DECL_TI(0) DECL_TI(1) DECL_TI(2) DECL_TI(3)
#undef DECL_TI

    if (isL1) {
#define LDA1(ti,j) { int k_ = (kh*8+(j))*32 + kc*8;                          \
        A##ti##_##j = ld8(k_ < 256 ? Wih1 + (size_t)R##ti*256 + k_           \
                                   : Whh1 + (size_t)R##ti*256 + (k_-256)); }
#define LDA1T(ti) LDA1(ti,0) LDA1(ti,1) LDA1(ti,2) LDA1(ti,3) \
                  LDA1(ti,4) LDA1(ti,5) LDA1(ti,6) LDA1(ti,7)
        LDA1T(0) LDA1T(1) LDA1T(2) LDA1T(3)
#undef LDA1T
#undef LDA1
    } else if (kh == 0) {
#define LDA0(ti,j) { int k_ = (0*5+(j))*32 + kc*8;                           \
        A##ti##_##j = ld8(k_ < 64 ? Wih0 + (size_t)R##ti*64 + k_             \
                                  : Whh0 + (size_t)R##ti*256 + (k_-64)); }
#define LDA0T(ti) LDA0(ti,0) LDA0(ti,1) LDA0(ti,2) LDA0(ti,3) LDA0(ti,4)
        LDA0T(0) LDA0T(1) LDA0T(2) LDA0T(3)
#undef LDA0T
#undef LDA0
    } else {
#define LDA0(ti,j) { int k_ = (1*5+(j))*32 + kc*8;                           \
        A##ti##_##j = ld8(k_ < 64 ? Wih0 + (size_t)R##ti*64 + k_             \
                                  : Whh0 + (size_t)R##ti*256 + (k_-64)); }
#define LDA0T(ti) LDA0(ti,0) LDA0(ti,1) LDA0(ti,2) LDA0(ti,3) LDA0(ti,4)
        LDA0T(0) LDA0T(1) LDA0T(2) LDA0T(3)
#undef LDA0T
#undef LDA0
    }

    // ---- activation duty: thread (lane = h-idx in quadrant, w = batch) ----
    const float* bA = isL1 ? bih1 : bih0;
    const float* bB = isL1 ? bhh1 : bhh0;
    const float bz0 = bA[      64*q + lane] + bB[      64*q + lane];
    const float bz1 = bA[256 + 64*q + lane] + bB[256 + 64*q + lane];
    const float bz2 = bA[512 + 64*q + lane] + bB[512 + 64*q + lane];
    const float bz3 = bA[768 + 64*q + lane] + bB[768 + 64*q + lane];
    float cst = 0.f;

    u32* const sBu = (u32*)sB;
    for (int i = tid; i < 4608; i += 512) sBu[i] = 0;   // incl. pad rows 8-15
    __syncthreads();   // zero-fill complete before x(0) staging

    // prologue: h(-1)=0 already in zeroed sB; stage only x(0)
    if (!isL1 && tid >= 256 && tid < 384) {
        int t2 = tid - 256, j = t2 >> 4, c = t2 & 15;
        float4 v = ((const float4*)(x + ((size_t)(batch0 + j) * TT) * DD))[c];
        int bidx = (c >> 1) * 72 + j * 4 + (c & 1) * 2;
        sBu[bidx]     = pkh(v.x, v.y);
        sBu[bidx + 1] = pkh(v.z, v.w);
    }

    for (int s = 0; s <= TT; ++s) {
        __syncthreads();   // staging for step s complete block-wide
        if (tid == 0) st32(&cflag[role], (u32)(s + 1));   // CF: staged step s

        const bool act_ = isL1 ? (s >= 1) : (s < TT);
        const int  snx  = s + 1;
        const bool stg0 = (!isL1) && (snx < TT);
        const bool stg1 = isL1 && (snx <= TT);

        // pre-issue ring-guard loads (checked after act; RTT hidden under MFMA)
        u32 cpre = 0xFFFFFFFFu;
        if (act_ && lane < 8) cpre = ld32(&cflag[lane]);

        if (act_) {
            f32x4 C0 = {0,0,0,0}, C1 = {0,0,0,0}, C2 = {0,0,0,0}, C3 = {0,0,0,0};
#define MST(j, ktb) { const f16x8 Bf = *(const f16x8*)(sB + (((ktb)+(j))*4 + kc)*144 + bcol*8); \
            C0 = __builtin_amdgcn_mfma_f32_16x16x32_f16(A0_##j, Bf, C0, 0,0,0); \
            C1 = __builtin_amdgcn_mfma_f32_16x16x32_f16(A1_##j, Bf, C1, 0,0,0); \
            C2 = __builtin_amdgcn_mfma_f32_16x16x32_f16(A2_##j, Bf, C2, 0,0,0); \
            C3 = __builtin_amdgcn_mfma_f32_16x16x32_f16(A3_##j, Bf, C3, 0,0,0); }
            if (isL1) {
                const int ktb = kh * 8;
                MST(0,ktb) MST(1,ktb) MST(2,ktb) MST(3,ktb)
                MST(4,ktb) MST(5,ktb) MST(6,ktb) MST(7,ktb)
            } else {
                const int ktb = kh * 5;
                MST(0,ktb) MST(1,ktb) MST(2,ktb) MST(3,ktb) MST(4,ktb)
            }
#undef MST
            if (bcol < 8) {   // C: col=batch(bcol), row=(kc)*4+reg within tile
                *(f32x4*)&part2[kh][bcol][mw*64 +  0 + kc*4] = C0;
                *(f32x4*)&part2[kh][bcol][mw*64 + 16 + kc*4] = C1;
                *(f32x4*)&part2[kh][bcol][mw*64 + 32 + kc*4] = C2;
                *(f32x4*)&part2[kh][bcol][mw*64 + 48 + kc*4] = C3;
            }
        }
        __syncthreads();   // part2 ready; all sB reads of step s done

        // ---- activation; own-direct LDS write + ring store ----
        if (act_) {
            float s0 = part2[0][w][      lane] + part2[1][w][      lane] + bz0;
            float s1 = part2[0][w][ 64 + lane] + part2[1][w][ 64 + lane] + bz1;
            float s2 = part2[0][w][128 + lane] + part2[1][w][128 + lane] + bz2;
            float s3 = part2[0][w][192 + lane] + part2[1][w][192 + lane] + bz3;
            float fi = sigf(s0), ff = sigf(s1), fg = tanhf_(s2), fo = sigf(s3);
            cst = ff * cst + fi * fg;
            float h = fo * tanhf_(cst);
            float hn = __shfl_down(h, 1);
            u32 hw = pkh(h, hn);

            if (!(lane & 1)) {   // own quadrant straight into own sB (step s+1)
                int nn = (64 * q + lane) >> 1;          // 32q + lane/2
                int base = isL1 ? 32 : 8;
                sBu[(base + (nn >> 2)) * 72 + w * 4 + (nn & 3)] = hw;
            }

            // ring-overwrite guard: all 8 blocks staged step s-2 (slack 2)
            const int tgt = s - 2;
            while (!__all(lane >= 8 || (int)cpre >= tgt)) {
                __builtin_amdgcn_s_sleep(1);
                if (lane < 8) cpre = ld32(&cflag[lane]);
            }
            if (!(lane & 1)) {   // packet: {epoch s+1 | 2 x f16}
                u64 v = ((u64)(u32)(s + 1) << 32) | (u64)hw;
                u64* dst = (isL1 ? ring1 + (size_t)((s - 1) & 3) * 1024
                                 : ring0 + (size_t)(s & 3) * 1024)
                           + q * 256 + w * 32 + (lane >> 1);
                st64(dst, v);
            }
        }

        // ---- finish staging for s+1: issue loads, retry until epochs match ----
        if (stg0 || stg1) {
            u64 v0A = 0, v0B = 0, v1A = 0, v1B = 0;
            bool k0A = true, k0B = true, k1A = true, k1B = true;
            const u64 *p0A = nullptr, *p0B = nullptr, *p1A = nullptr, *p1B = nullptr;
            if (!(!isL1 && nq == q)) {   // L0 skips own h0 quadrant (own-direct)
                const u64* b0 = ring0 + (size_t)((snx - 1) & 3) * 1024
                                + (nq << 8) + (n_ & 31);
                p0A = b0 + jA * 32; p0B = b0 + jB * 32;
                v0A = ld64(p0A); v0B = ld64(p0B);
                k0A = false; k0B = false;
            }
            if (stg1 && !(nq == q && snx >= 2)) {   // L1 skips own h1 (snx>=2)
                const u64* b1 = ring1 + (size_t)((snx + 2) & 3) * 1024
                                + (nq << 8) + (n_ & 31);
                p1A = b1 + jA * 32; p1B = b1 + jB * 32;
                v1A = ld64(p1A); v1B = ld64(p1B);
                k1A = false; k1B = false;
            }
            float4 xreg;
            const bool doX = stg0 && (tid >= 256) && (tid < 384);
            if (doX) {
                int t2 = tid - 256, j = t2 >> 4, c = t2 & 15;
                xreg = ((const float4*)(x + ((size_t)(batch0 + j) * TT + snx) * DD))[c];
            }
            const u32 e0 = (u32)snx;
            const u32 e1 = (snx >= 2) ? (u32)snx : 0u;
            for (;;) {
                if (!k0A && (u32)(v0A >> 32) == e0) k0A = true;
                if (!k0B && (u32)(v0B >> 32) == e0) k0B = true;
                if (!k1A && (u32)(v1A >> 32) == e1) k1A = true;
                if (!k1B && (u32)(v1B >> 32) == e1) k1B = true;
                if (k0A & k0B & k1A & k1B) break;
                if (!k0A) v0A = ld64(p0A);
                if (!k0B) v0B = ld64(p0B);
                if (!k1A) v1A = ld64(p1A);
                if (!k1B) v1B = ld64(p1B);
            }
            if (p0A) {
                const int base = isL1 ? 0 : 8;
                sBu[(base + (n_ >> 2)) * 72 + jA * 4 + (n_ & 3)] = (u32)v0A;
                sBu[(base + (n_ >> 2)) * 72 + jB * 4 + (n_ & 3)] = (u32)v0B;
            }
            if (p1A) {
                sBu[(32 + (n_ >> 2)) * 72 + jA * 4 + (n_ & 3)] = (u32)v1A;
                sBu[(32 + (n_ >> 2)) * 72 + jB * 4 + (n_ & 3)] = (u32)v1B;
            }
            if (doX) {
                int t2 = tid - 256, j = t2 >> 4, c = t2 & 15;
                int bidx = (c >> 1) * 72 + j * 4 + (c & 1) * 2;
                sBu[bidx]     = pkh(xreg.x, xreg.y);
                sBu[bidx + 1] = pkh(xreg.z, xreg.w);
            }
        }
    }

    // ---- final FC on h1(TT-1): slot 3, epoch TT+1; role-4 block per group ----
    if (isL1 && q == 0) {
        const u32 ef = (u32)(TT + 1);
#pragma unroll
        for (int pp = 0; pp < 2; ++pp) {
            int p = tid + pp * 512;
            int j = p >> 7, n = p & 127;
            const u64* a = ring1 + 3 * 1024 + (n >> 5) * 256 + j * 32 + (n & 31);
            u64 v;
            do { v = ld64(a); } while ((u32)(v >> 32) != ef);
            sBu[j * 128 + n] = (u32)v;   // flat [batch][128 u32]
        }
        __syncthreads();
        const int j = tid >> 6, l2 = tid & 63;
        const int o = l2 >> 4, kk = l2 & 15;
        float ssum = 0.f;
#pragma unroll
        for (int m = 0; m < 16; ++m) {
            int k = kk * 16 + m;
            ssum += (float)sB[j * 256 + k] * fcW[o * HH + k];
        }
#pragma unroll
        for (int off = 8; off; off >>= 1) ssum += __shfl_down(ssum, off);
        if (kk == 0) out[(batch0 + j) * 4 + o] = ssum + fcb[o];
    }
}

extern "C" void kernel_launch(void* const* d_in, const int* in_sizes, int n_in,
                              void* d_out, int out_size, void* d_ws, size_t ws_size,
                              hipStream_t stream)
{
    (void)in_sizes; (void)n_in; (void)out_size; (void)ws_size;
    const float* x    = (const float*)d_in[0];
    const float* Wih0 = (const float*)d_in[1];
    const float* Whh0 = (const float*)d_in[2];
    const float* bih0 = (const float*)d_in[3];
    const float* bhh0 = (const float*)d_in[4];
    const float* Wih1 = (const float*)d_in[5];
    const float* Whh1 = (const float*)d_in[6];
    const float* bih1 = (const float*)d_in[7];
    const float* bhh1 = (const float*)d_in[8];
    const float* fcW  = (const float*)d_in[9];
    const float* fcb  = (const float*)d_in[10];
    float* out = (float*)d_out;

    // ws: h0ring 1MB (32 grp x 4 slot x 1024 u64) | h1ring 1MB | cflags 2KB
    u64* h0ring = (u64*)d_ws;
    u64* h1ring = (u64*)((char*)d_ws + 1048576);
    u32* cflags = (u32*)((char*)d_ws + 2097152);

    hipMemsetAsync(d_ws, 0, 2097152 + 2048, stream);   // epoch 0 == h(-1)=0

    lstm_persist<<<dim3(256), dim3(512), 0, stream>>>(
        x, Wih0, Whh0, bih0, bhh0, Wih1, Whh1, bih1, bhh1, fcW, fcb, out,
        h0ring, h1ring, cflags);
}